// Round 1
// baseline (33.819 us; speedup 1.0000x reference)
//
#include <hip/hip_runtime.h>

#define BATCH 1024
#define NUM_GENES 20000
#define NONGENE_DIM 64
#define EMB_DIM 32
#define INPUT_DIM (NUM_GENES + NONGENE_DIM)   // 20064
#define G4 (NUM_GENES / 4)                    // 5000 float4 per output row

// ws layout: [0 .. NUM_GENES)            gene_term
//            [NUM_GENES .. NUM_GENES+B)  ng_term
__global__ void dlge_precompute(const float* __restrict__ x,
                                const float* __restrict__ emb,
                                const float* __restrict__ W,
                                float* __restrict__ ws) {
    const int tid = blockIdx.x * blockDim.x + threadIdx.x;
    if (tid < NUM_GENES) {
        // gene_term[g] = dot(emb[g, :], W[65:97])
        const float4* e4 = reinterpret_cast<const float4*>(emb + (size_t)tid * EMB_DIM);
        float acc = 0.0f;
#pragma unroll
        for (int k = 0; k < EMB_DIM / 4; ++k) {
            const float4 e = e4[k];
            acc += e.x * W[NONGENE_DIM + 1 + 4 * k + 0]
                 + e.y * W[NONGENE_DIM + 1 + 4 * k + 1]
                 + e.z * W[NONGENE_DIM + 1 + 4 * k + 2]
                 + e.w * W[NONGENE_DIM + 1 + 4 * k + 3];
        }
        ws[tid] = acc;
    } else if (tid < NUM_GENES + BATCH) {
        // ng_term[i] = dot(x[i, 20000:20064], W[0:64])
        const int row = tid - NUM_GENES;
        const float4* n4 = reinterpret_cast<const float4*>(
            x + (size_t)row * INPUT_DIM + NUM_GENES);
        float acc = 0.0f;
#pragma unroll
        for (int k = 0; k < NONGENE_DIM / 4; ++k) {
            const float4 v = n4[k];
            acc += v.x * W[4 * k + 0] + v.y * W[4 * k + 1]
                 + v.z * W[4 * k + 2] + v.w * W[4 * k + 3];
        }
        ws[NUM_GENES + row] = acc;
    }
}

__global__ void dlge_main(const float* __restrict__ x,
                          const float* __restrict__ ws,
                          const float* __restrict__ W,
                          const float* __restrict__ bptr,
                          float* __restrict__ y) {
    const int row = blockIdx.y;
    const int j = blockIdx.x * blockDim.x + threadIdx.x;  // float4 index in row
    if (j >= G4) return;

    const float wx = W[NONGENE_DIM];                       // W[64]
    const float s  = ws[NUM_GENES + row] + bptr[0];        // ng_term[row] + b

    const float4 x4 = reinterpret_cast<const float4*>(x + (size_t)row * INPUT_DIM)[j];
    const float4 g4 = reinterpret_cast<const float4*>(ws)[j];  // gene_term chunk

    float4 o;
    o.x = s + x4.x * wx + g4.x;
    o.y = s + x4.y * wx + g4.y;
    o.z = s + x4.z * wx + g4.z;
    o.w = s + x4.w * wx + g4.w;

    reinterpret_cast<float4*>(y + (size_t)row * NUM_GENES)[j] = o;
}

extern "C" void kernel_launch(void* const* d_in, const int* in_sizes, int n_in,
                              void* d_out, int out_size, void* d_ws, size_t ws_size,
                              hipStream_t stream) {
    const float* x   = (const float*)d_in[0];
    const float* emb = (const float*)d_in[1];
    const float* W   = (const float*)d_in[2];
    const float* b   = (const float*)d_in[3];
    float* y  = (float*)d_out;
    float* ws = (float*)d_ws;

    // 1) precompute gene_term (20000) + ng_term (1024) into ws
    {
        const int total = NUM_GENES + BATCH;
        const int blocks = (total + 255) / 256;
        dlge_precompute<<<blocks, 256, 0, stream>>>(x, emb, W, ws);
    }

    // 2) main elementwise pass: y[i,g] = ng[i] + x[i,g]*wx + gt[g] + b
    {
        dim3 grid((G4 + 255) / 256, BATCH);
        dlge_main<<<grid, 256, 0, stream>>>(x, ws, W, b, y);
    }
}